// Round 6
// baseline (376.475 us; speedup 1.0000x reference)
//
#include <hip/hip_runtime.h>
#include <stdint.h>

// ---------------------------------------------------------------------------
// SingleHeadedAttention (Mega-style, laplacian attn fn, causal, T5 rel bias)
// B=4, S=2048, DIM=1024, DQK=128, DV=1024.  fp32 in/out, bf16 MFMA internals.
// R5: wave-private register GEMM. No LDS, no barriers in the GEMM kernels.
//     Each wave computes a 64x64 tile (4x4 16x16x32 MFMAs, ratio 16 MFMA per
//     8 fragment loads); A/B fragments are loaded straight from row-major
//     global memory as strided global_load_dwordx4 (lane16=row, quad*8=k) and
//     double-buffered in registers (compiler inserts vmcnt(8) on dependence).
//     R2-R4 post-mortem: barrier+LDS round-trip kept step time ~1100cyc
//     regardless of ring depth or blocks/CU; this removes the shared state.
// ---------------------------------------------------------------------------

#define B_   4
#define S_   2048
#define DIM_ 1024
#define DQK  128
#define DV   1024
#define NQV  (DQK + DV)   // 1152

typedef __attribute__((ext_vector_type(8))) short short8;   // 8 bf16 (4 VGPRs)
typedef __attribute__((ext_vector_type(4))) float f32x4;    // MFMA C/D

__device__ __forceinline__ uint16_t f32_to_bf16(float f) {
  uint32_t u = __float_as_uint(f);
  u += 0x7FFFu + ((u >> 16) & 1u);          // round-to-nearest-even
  return (uint16_t)(u >> 16);
}

__device__ __forceinline__ float silu_f(float x) {
  return x / (1.0f + expf(-x));
}

__device__ __forceinline__ float laplacian_attn(float x) {
  // (1 + erf((x - sqrt(0.5)) / sqrt(0.5*pi))) * 0.5
  return 0.5f * (1.0f + erff((x - 0.70710678118654752f) * 0.79788456080286536f));
}

// ---- wave-private 64x64 GEMM: C = A(rows row0..+63) * Bt(rows col0..+63)^T
// A: [M][lda] bf16 row-major, Bt: [N][ldb] bf16 row-major, k-contiguous.
// K multiple of 64, K >= 64. Fragment loads: lane16 = row-in-16-tile,
// quad*8 = k-octet -> strided global_load_dwordx4, 16B aligned.
// Register double-buffer: set0/set1 alternate, one 8-load batch in flight.
__device__ __forceinline__ void wave_gemm(
    const uint16_t* __restrict__ A, int lda,
    const uint16_t* __restrict__ Bt, int ldb,
    long row0, long col0, int K, f32x4 acc[4][4])
{
  const int lane   = threadIdx.x & 63;
  const int lane16 = lane & 15;
  const int quad   = lane >> 4;

  const uint16_t* pa[4];
  const uint16_t* pb[4];
  #pragma unroll
  for (int mt = 0; mt < 4; mt++)
    pa[mt] = A + (row0 + mt * 16 + lane16) * (long)lda + quad * 8;
  #pragma unroll
  for (int nt = 0; nt < 4; nt++)
    pb[nt] = Bt + (col0 + nt * 16 + lane16) * (long)ldb + quad * 8;

  #pragma unroll
  for (int mt = 0; mt < 4; mt++)
    #pragma unroll
    for (int nt = 0; nt < 4; nt++) {
      f32x4 z = {0.0f, 0.0f, 0.0f, 0.0f};
      acc[mt][nt] = z;
    }

  short8 fa0[4], fb0[4], fa1[4], fb1[4];

  auto loads = [&](short8 fa[4], short8 fb[4], int k) {
    #pragma unroll
    for (int mt = 0; mt < 4; mt++)
      fa[mt] = *(const short8*)(pa[mt] + k);
    #pragma unroll
    for (int nt = 0; nt < 4; nt++)
      fb[nt] = *(const short8*)(pb[nt] + k);
  };
  auto mfmas = [&](short8 fa[4], short8 fb[4]) {
    #pragma unroll
    for (int mt = 0; mt < 4; mt++)
      #pragma unroll
      for (int nt = 0; nt < 4; nt++)
        acc[mt][nt] = __builtin_amdgcn_mfma_f32_16x16x32_bf16(
            fa[mt], fb[nt], acc[mt][nt], 0, 0, 0);
  };

  loads(fa0, fb0, 0);
  loads(fa1, fb1, 32);
  for (int k = 64; k < K; k += 64) {
    mfmas(fa0, fb0);
    loads(fa0, fb0, k);
    mfmas(fa1, fb1);
    loads(fa1, fb1, k + 32);
  }
  mfmas(fa0, fb0);
  mfmas(fa1, fb1);
}

// block = 256 threads = 4 independent waves, 2x2 over a 128x128 block tile.
// wave w -> rows +(w>>1)*64, cols +(w&1)*64.
// epilogue: row = wrow + mt*16 + quad*4 + r ; col = wcol + nt*16 + lane16
#define WAVE_PREAMBLE                                  \
  int lane = threadIdx.x & 63;                         \
  int wave = threadIdx.x >> 6;                         \
  int lane16 = lane & 15;                              \
  int quad = lane >> 4;                                \
  int wrow = (wave >> 1) * 64;                         \
  int wcol = (wave & 1) * 64;

// ---- prep kernels ----------------------------------------------------------

__global__ __launch_bounds__(256) void k_convert_x(
    const float* __restrict__ in, uint16_t* __restrict__ out, int n4)
{
  int i = blockIdx.x * blockDim.x + threadIdx.x;
  if (i >= n4) return;
  float4 v = ((const float4*)in)[i];
  ushort4 o;
  o.x = f32_to_bf16(v.x); o.y = f32_to_bf16(v.y);
  o.z = f32_to_bf16(v.z); o.w = f32_to_bf16(v.w);
  ((ushort4*)out)[i] = o;
}

// in: fp32 [R][C] -> out: bf16 [C][R]  (R,C mult of 32), block (32,8)
__global__ __launch_bounds__(256) void k_transpose_f32_bf16(
    const float* __restrict__ in, uint16_t* __restrict__ out, int R, int C)
{
  __shared__ float tile[32][33];
  int c0 = blockIdx.x * 32, r0 = blockIdx.y * 32;
  int tx = threadIdx.x, ty = threadIdx.y;
  #pragma unroll
  for (int k = 0; k < 32; k += 8)
    tile[ty + k][tx] = in[(long)(r0 + ty + k) * C + c0 + tx];
  __syncthreads();
  #pragma unroll
  for (int k = 0; k < 32; k += 8)
    out[(long)(c0 + ty + k) * R + r0 + tx] = f32_to_bf16(tile[tx][ty + k]);
}

// v bf16 [B*S][DV] -> vT bf16 [B][DV][S], block (32,8), grid (DV/32, S/32, B)
__global__ __launch_bounds__(256) void k_transpose_v(
    const uint16_t* __restrict__ v, uint16_t* __restrict__ vT)
{
  __shared__ uint16_t tile[32][33];
  int b = blockIdx.z;
  int n0 = blockIdx.x * 32, j0 = blockIdx.y * 32;
  int tx = threadIdx.x, ty = threadIdx.y;
  #pragma unroll
  for (int k = 0; k < 32; k += 8)
    tile[ty + k][tx] = v[((long)b * S_ + j0 + ty + k) * DV + n0 + tx];
  __syncthreads();
  #pragma unroll
  for (int k = 0; k < 32; k += 8)
    vT[((long)b * DV + n0 + ty + k) * S_ + j0 + tx] = tile[tx][ty + k];
}

// bias_n[n] = rel_bias[bucket(n)] * sqrt(DQK), n = i - j in [0, S)
__global__ __launch_bounds__(256) void k_bias(
    const float* __restrict__ rel, float* __restrict__ bias_n)
{
  int n = blockIdx.x * blockDim.x + threadIdx.x;
  if (n >= S_) return;
  int bucket;
  if (n < 16) {
    bucket = n;
  } else {
    float tt = logf((float)n * 0.0625f) / 2.0794415416798357f * 16.0f;
    int vl = 16 + (int)tt;
    bucket = vl < 31 ? vl : 31;
  }
  bias_n[n] = rel[bucket] * 11.313708498984761f;   // * sqrt(128)
}

// ---- GEMM kernels ----------------------------------------------------------

// fused projections: block tile 128x128; bx==0 -> q/k epilogue (cols 0..127),
// bx>=1 -> v epilogue. wT: [NQV][DIM] bf16 (rows 0..127 wqk^T, 128.. wv^T).
__global__ __launch_bounds__(256) void k_gemm_qkv(
    const uint16_t* __restrict__ xb, const uint16_t* __restrict__ wT,
    const float* __restrict__ bqk, const float* __restrict__ gamma,
    const float* __restrict__ beta, const float* __restrict__ bv,
    uint16_t* __restrict__ qb, uint16_t* __restrict__ kb,
    uint16_t* __restrict__ vb)
{
  long i0 = (long)blockIdx.y * 128;
  long n0 = (long)blockIdx.x * 128;
  WAVE_PREAMBLE
  f32x4 acc[4][4];
  wave_gemm(xb, DIM_, wT, DIM_, i0 + wrow, n0 + wcol, DIM_, acc);
  if (n0 == 0) {
    #pragma unroll
    for (int mt = 0; mt < 4; mt++)
      #pragma unroll
      for (int nt = 0; nt < 4; nt++)
        #pragma unroll
        for (int r = 0; r < 4; r++) {
          long row = i0 + wrow + mt * 16 + quad * 4 + r;
          int col = wcol + nt * 16 + lane16;         // 0..127 = DQK
          float vsum = acc[mt][nt][r] + bqk[col];
          float s = silu_f(vsum);
          float qv = s * gamma[col] + beta[col];
          float kv = s * gamma[DQK + col] + beta[DQK + col];
          qb[row * DQK + col] = f32_to_bf16(qv);
          kb[row * DQK + col] = f32_to_bf16(kv);
        }
  } else {
    long v0 = n0 - DQK;
    #pragma unroll
    for (int mt = 0; mt < 4; mt++)
      #pragma unroll
      for (int nt = 0; nt < 4; nt++)
        #pragma unroll
        for (int r = 0; r < 4; r++) {
          long row = i0 + wrow + mt * 16 + quad * 4 + r;
          long gc = v0 + wcol + nt * 16 + lane16;
          float vsum = acc[mt][nt][r] + bv[gc];
          vb[row * DV + gc] = f32_to_bf16(silu_f(vsum));
        }
  }
}

// attn = laplacian(q@k^T / S + bias[i-j]) masked causal, bf16 [B][S][S]
// grid (S/128 jt, S/128 it, B); strictly-upper tiles skipped (never read)
__global__ __launch_bounds__(256) void k_gemm_sim(
    const uint16_t* __restrict__ qb, const uint16_t* __restrict__ kb,
    const float* __restrict__ bias_n, uint16_t* __restrict__ attn)
{
  int bt = blockIdx.z;
  int it = blockIdx.y, jt = blockIdx.x;
  if (jt > it) return;
  long i0 = (long)it * 128, j0 = (long)jt * 128;
  const uint16_t* q = qb + (long)bt * S_ * DQK;
  const uint16_t* k = kb + (long)bt * S_ * DQK;
  WAVE_PREAMBLE
  f32x4 acc[4][4];
  wave_gemm(q, DQK, k, DQK, i0 + wrow, j0 + wcol, DQK, acc);
  uint16_t* ab = attn + (long)bt * S_ * S_;
  #pragma unroll
  for (int mt = 0; mt < 4; mt++)
    #pragma unroll
    for (int nt = 0; nt < 4; nt++)
      #pragma unroll
      for (int r = 0; r < 4; r++) {
        long i = i0 + wrow + mt * 16 + quad * 4 + r;
        long j = j0 + wcol + nt * 16 + lane16;
        float aval = 0.0f;
        if (j <= i) {
          float sim = acc[mt][nt][r] * (1.0f / 2048.0f) + bias_n[i - j];
          aval = laplacian_attn(sim);
        }
        ab[i * S_ + j] = f32_to_bf16(aval);
      }
}

// out = attn @ v (fp32 out), K causally bounded at i0+128.
// grid (DV/128, 64): y = bt*16 + tt; it = (bt&1) ? 15-tt : tt so co-resident
// block groups get ~constant K sums.
__global__ __launch_bounds__(256) void k_gemm_out(
    const uint16_t* __restrict__ attn, const uint16_t* __restrict__ vT,
    float* __restrict__ out)
{
  int y  = blockIdx.y;
  int bt = y >> 4;
  int tt = y & 15;
  int it = (bt & 1) ? (15 - tt) : tt;
  long i0 = (long)it * 128;
  long n0 = (long)blockIdx.x * 128;
  int K = (int)i0 + 128;                           // j <= i  => k < i0+128
  WAVE_PREAMBLE
  f32x4 acc[4][4];
  wave_gemm(attn + (long)bt * S_ * S_, S_,
            vT + (long)bt * DV * S_, S_, i0 + wrow, n0 + wcol, K, acc);
  #pragma unroll
  for (int mt = 0; mt < 4; mt++)
    #pragma unroll
    for (int nt = 0; nt < 4; nt++)
      #pragma unroll
      for (int r = 0; r < 4; r++) {
        int row = wrow + mt * 16 + quad * 4 + r;
        int col = wcol + nt * 16 + lane16;
        out[((long)bt * S_ + i0 + row) * DV + n0 + col] = acc[mt][nt][r];
      }
}

// ---------------------------------------------------------------------------

extern "C" void kernel_launch(void* const* d_in, const int* in_sizes, int n_in,
                              void* d_out, int out_size, void* d_ws, size_t ws_size,
                              hipStream_t stream)
{
  const float* x     = (const float*)d_in[0];
  const float* wqk   = (const float*)d_in[1];
  const float* bqk   = (const float*)d_in[2];
  const float* gamma = (const float*)d_in[3];
  const float* beta  = (const float*)d_in[4];
  const float* wv    = (const float*)d_in[5];
  const float* bv    = (const float*)d_in[6];
  const float* rel   = (const float*)d_in[7];
  float* out = (float*)d_out;

  char* ws = (char*)d_ws;
  size_t off = 0;
  uint16_t* xb     = (uint16_t*)(ws + off); off += (size_t)B_ * S_ * DIM_ * 2;  // 16 MB
  uint16_t* wT     = (uint16_t*)(ws + off); off += (size_t)NQV * DIM_ * 2;      // 2.25 MB
  uint16_t* qb     = (uint16_t*)(ws + off); off += (size_t)B_ * S_ * DQK * 2;   // 2 MB
  uint16_t* kb     = (uint16_t*)(ws + off); off += (size_t)B_ * S_ * DQK * 2;   // 2 MB
  uint16_t* vb     = (uint16_t*)(ws + off); off += (size_t)B_ * S_ * DV * 2;    // 16 MB
  uint16_t* vT     = (uint16_t*)(ws + off); off += (size_t)B_ * DV * S_ * 2;    // 16 MB
  uint16_t* attn   = (uint16_t*)(ws + off); off += (size_t)B_ * S_ * S_ * 2;    // 32 MB
  float*    bias_n = (float*)(ws + off);    off += (size_t)S_ * 4;              // 8 KB

  const int n_x = B_ * S_ * DIM_;
  k_convert_x<<<dim3((n_x / 4 + 255) / 256), dim3(256), 0, stream>>>(x, xb, n_x / 4);
  k_transpose_f32_bf16<<<dim3(DQK / 32, DIM_ / 32), dim3(32, 8), 0, stream>>>(wqk, wT, DIM_, DQK);
  k_transpose_f32_bf16<<<dim3(DV / 32, DIM_ / 32), dim3(32, 8), 0, stream>>>(wv, wT + (size_t)DQK * DIM_, DIM_, DV);
  k_bias<<<dim3(S_ / 256), dim3(256), 0, stream>>>(rel, bias_n);

  k_gemm_qkv<<<dim3(NQV / 128, B_ * S_ / 128), dim3(256), 0, stream>>>(
      xb, wT, bqk, gamma, beta, bv, qb, kb, vb);
  k_transpose_v<<<dim3(DV / 32, S_ / 32, B_), dim3(32, 8), 0, stream>>>(vb, vT);
  k_gemm_sim<<<dim3(S_ / 128, S_ / 128, B_), dim3(256), 0, stream>>>(qb, kb, bias_n, attn);
  k_gemm_out<<<dim3(DV / 128, 64), dim3(256), 0, stream>>>(attn, vT, out);
}

// Round 7
// 268.594 us; speedup vs baseline: 1.4017x; 1.4017x over previous
//
#include <hip/hip_runtime.h>
#include <stdint.h>

// ---------------------------------------------------------------------------
// SingleHeadedAttention (Mega-style, laplacian attn fn, causal, T5 rel bias)
// B=4, S=2048, DIM=1024, DQK=128, DV=1024.  fp32 in/out, bf16 MFMA internals.
// R6: TILED global layouts + single-wave barrier-free pipelined GEMMs.
//   TILED: element (row,k) of [R][K] at
//     ((row>>4)*(K>>5) + (k>>5))*512 + ((k>>3)&3)*128 + (row&15)*8 + (k&7)
//   (16-row x 32-k 1KB blocks). One global_load_lds inst stages one block
//   from CONTIGUOUS global memory; lane l receives exactly its MFMA fragment
//   (row16=l&15, oct=l>>4) at lds base + l*16. Fragment ds_read_b128 at
//   base+lane*16 is a linear 1KB sweep -> zero bank conflicts.
//   GEMM blocks are 1 wave (64x64 tile, acc[4][4]); wave-private 4-slot LDS
//   ring (32 KB -> 5 blocks/CU), 3 tiles in flight, s_waitcnt vmcnt(16/8/0),
//   NO barriers. vT transpose eliminated (qkv epilogue writes vT tiled).
// ---------------------------------------------------------------------------

#define B_   4
#define S_   2048
#define DIM_ 1024
#define DQK  128
#define DV   1024
#define NQV  1152

typedef __attribute__((ext_vector_type(8))) short short8;   // 8 bf16
typedef __attribute__((ext_vector_type(4))) float f32x4;    // MFMA C/D

__device__ __forceinline__ uint16_t f32_to_bf16(float f) {
  uint32_t u = __float_as_uint(f);
  u += 0x7FFFu + ((u >> 16) & 1u);          // round-to-nearest-even
  return (uint16_t)(u >> 16);
}

__device__ __forceinline__ float silu_f(float x) {
  return x / (1.0f + expf(-x));
}

__device__ __forceinline__ float laplacian_attn(float x) {
  return 0.5f * (1.0f + erff((x - 0.70710678118654752f) * 0.79788456080286536f));
}

__device__ __forceinline__ void async_ld16(const void* g, void* l) {
  __builtin_amdgcn_global_load_lds(
      (const __attribute__((address_space(1))) void*)g,
      (__attribute__((address_space(3))) void*)l, 16, 0, 0);
}

// ---- single-wave 64x64 GEMM on TILED operands -----------------------------
// A: tiled [RA][K], row-blocks rbA..rbA+3; Bt: tiled [RB][K], rbB..rbB+3.
// KBa/KBb = K>>5 (k-blocks per row-block). nkb = k-blocks to process (>=2).
// lds: 4 slots x 4096 elems (8 KB each: A 2048 + B 2048). No barriers.
__device__ __forceinline__ void wave_gemm_t(
    const uint16_t* __restrict__ A, int KBa, int rbA,
    const uint16_t* __restrict__ Bt, int KBb, int rbB,
    int nkb, f32x4 acc[4][4], uint16_t* lds)
{
  const int lane = threadIdx.x & 63;

  const uint16_t* pa[4];
  const uint16_t* pb[4];
  #pragma unroll
  for (int mt = 0; mt < 4; mt++)
    pa[mt] = A + (size_t)(rbA + mt) * KBa * 512 + lane * 8;
  #pragma unroll
  for (int nt = 0; nt < 4; nt++)
    pb[nt] = Bt + (size_t)(rbB + nt) * KBb * 512 + lane * 8;

  #pragma unroll
  for (int mt = 0; mt < 4; mt++)
    #pragma unroll
    for (int nt = 0; nt < 4; nt++) {
      f32x4 z = {0.0f, 0.0f, 0.0f, 0.0f};
      acc[mt][nt] = z;
    }

  auto stage = [&](int slot, int kb) {     // 8 vmcnt-counted insts
    uint16_t* d = lds + slot * 4096;
    #pragma unroll
    for (int mt = 0; mt < 4; mt++)
      async_ld16(pa[mt] + kb * 512, d + mt * 512);
    #pragma unroll
    for (int nt = 0; nt < 4; nt++)
      async_ld16(pb[nt] + kb * 512, d + 2048 + nt * 512);
  };

  auto compute = [&](int slot) {
    const uint16_t* la = lds + slot * 4096 + lane * 8;
    short8 af[4], bf[4];
    #pragma unroll
    for (int mt = 0; mt < 4; mt++)
      af[mt] = *(const short8*)(la + mt * 512);
    #pragma unroll
    for (int nt = 0; nt < 4; nt++)
      bf[nt] = *(const short8*)(la + 2048 + nt * 512);
    #pragma unroll
    for (int mt = 0; mt < 4; mt++)
      #pragma unroll
      for (int nt = 0; nt < 4; nt++)
        acc[mt][nt] = __builtin_amdgcn_mfma_f32_16x16x32_bf16(
            af[mt], bf[nt], acc[mt][nt], 0, 0, 0);
  };

  // prologue: up to 3 tiles in flight
  stage(0, 0);
  stage(1, 1);
  if (nkb > 2) stage(2, 2);

  for (int k = 0; k <= nkb - 3; k++) {
    asm volatile("s_waitcnt vmcnt(16)" ::: "memory");   // tile k landed
    if (k + 3 < nkb) stage((k + 3) & 3, k + 3);
    compute(k & 3);
  }
  asm volatile("s_waitcnt vmcnt(8)" ::: "memory");
  compute((nkb - 2) & 3);
  asm volatile("s_waitcnt vmcnt(0)" ::: "memory");
  compute((nkb - 1) & 3);
}

// ---- prep kernels ----------------------------------------------------------

// x fp32 [8192][1024] -> xb TILED bf16. t indexes output 16B-octets linearly:
// out = xb + t*8 (coalesced); src = 8 consecutive f32 of row ib*16+i16.
__global__ __launch_bounds__(256) void k_prep_x(
    const float* __restrict__ x, uint16_t* __restrict__ xb)
{
  int t = blockIdx.x * 256 + threadIdx.x;      // 0 .. 8192*128-1
  int i16 = t & 15, oct = (t >> 4) & 3, kb = (t >> 6) & 31, ib = t >> 11;
  const float* src = x + (size_t)(ib * 16 + i16) * DIM_ + kb * 32 + oct * 8;
  float4 a = *(const float4*)src;
  float4 b = *(const float4*)(src + 4);
  short8 o;
  o[0] = f32_to_bf16(a.x); o[1] = f32_to_bf16(a.y);
  o[2] = f32_to_bf16(a.z); o[3] = f32_to_bf16(a.w);
  o[4] = f32_to_bf16(b.x); o[5] = f32_to_bf16(b.y);
  o[6] = f32_to_bf16(b.z); o[7] = f32_to_bf16(b.w);
  *(short8*)(xb + (size_t)t * 8) = o;
}

// wqk [1024][128], wv [1024][1024] fp32 -> wT TILED bf16 rows n=0..1151, K=1024
__global__ __launch_bounds__(256) void k_prep_w(
    const float* __restrict__ wqk, const float* __restrict__ wv,
    uint16_t* __restrict__ wT)
{
  int t = blockIdx.x * 256 + threadIdx.x;      // 0 .. 1152*128-1
  int n16 = t & 15, oct = (t >> 4) & 3, kb = (t >> 6) & 31, nb = t >> 11;
  int n = nb * 16 + n16;
  int k0 = kb * 32 + oct * 8;
  short8 o;
  if (n < DQK) {
    #pragma unroll
    for (int j = 0; j < 8; j++)
      o[j] = f32_to_bf16(wqk[(size_t)(k0 + j) * DQK + n]);
  } else {
    int nn = n - DQK;
    #pragma unroll
    for (int j = 0; j < 8; j++)
      o[j] = f32_to_bf16(wv[(size_t)(k0 + j) * DV + nn]);
  }
  *(short8*)(wT + (size_t)t * 8) = o;
}

// bias_n[n] = rel_bias[bucket(n)] * sqrt(DQK)
__global__ __launch_bounds__(256) void k_bias(
    const float* __restrict__ rel, float* __restrict__ bias_n)
{
  int n = blockIdx.x * blockDim.x + threadIdx.x;
  if (n >= S_) return;
  int bucket;
  if (n < 16) {
    bucket = n;
  } else {
    float tt = logf((float)n * 0.0625f) / 2.0794415416798357f * 16.0f;
    int vl = 16 + (int)tt;
    bucket = vl < 31 ? vl : 31;
  }
  bias_n[n] = rel[bucket] * 11.313708498984761f;
}

// ---- GEMM kernels (single-wave blocks) -------------------------------------

// fused projections. grid (18, 128). bx<2 -> q/k epilogue; else v -> vT tiled.
__global__ __launch_bounds__(64) void k_gemm_qkv(
    const uint16_t* __restrict__ xb, const uint16_t* __restrict__ wT,
    const float* __restrict__ bqk, const float* __restrict__ gamma,
    const float* __restrict__ beta, const float* __restrict__ bv,
    uint16_t* __restrict__ qb, uint16_t* __restrict__ kb,
    uint16_t* __restrict__ vT)
{
  __shared__ uint16_t lds[4 * 4096];
  int bx = blockIdx.x, by = blockIdx.y;
  f32x4 acc[4][4];
  wave_gemm_t(xb, DIM_ >> 5, by * 4, wT, DIM_ >> 5, bx * 4, DIM_ >> 5, acc, lds);
  int lane = threadIdx.x & 63;
  int lane16 = lane & 15, quad = lane >> 4;

  if (bx < 2) {
    #pragma unroll
    for (int nt = 0; nt < 4; nt++) {
      int col = bx * 64 + nt * 16 + lane16;        // 0..127
      float bb = bqk[col];
      float g0 = gamma[col], b0 = beta[col];
      float g1 = gamma[DQK + col], b1 = beta[DQK + col];
      int coff = (col >> 5) * 512 + ((col >> 3) & 3) * 128 + (col & 7);
      #pragma unroll
      for (int mt = 0; mt < 4; mt++) {
        size_t base = (size_t)((by * 4 + mt) * 4) * 512 + coff + (quad * 4) * 8;
        #pragma unroll
        for (int r = 0; r < 4; r++) {
          float s = silu_f(acc[mt][nt][r] + bb);
          qb[base + r * 8] = f32_to_bf16(s * g0 + b0);
          kb[base + r * 8] = f32_to_bf16(s * g1 + b1);
        }
      }
    }
  } else {
    int b = by >> 5;                                // batch
    uint16_t* vt = vT + (size_t)b * DV * S_;
    #pragma unroll
    for (int nt = 0; nt < 4; nt++) {
      int n = (bx - 2) * 64 + nt * 16 + lane16;     // 0..1023
      float bb = bv[n];
      #pragma unroll
      for (int mt = 0; mt < 4; mt++) {
        int j0l = (by & 31) * 64 + mt * 16 + quad * 4;   // local seq, 4-aligned
        uint16_t v0 = f32_to_bf16(silu_f(acc[mt][nt][0] + bb));
        uint16_t v1 = f32_to_bf16(silu_f(acc[mt][nt][1] + bb));
        uint16_t v2 = f32_to_bf16(silu_f(acc[mt][nt][2] + bb));
        uint16_t v3 = f32_to_bf16(silu_f(acc[mt][nt][3] + bb));
        size_t off = (size_t)((n >> 4) * 64 + (j0l >> 5)) * 512 +
                     ((j0l >> 3) & 3) * 128 + (n & 15) * 8 + (j0l & 7);
        uint2 pk;
        pk.x = (uint32_t)v0 | ((uint32_t)v1 << 16);
        pk.y = (uint32_t)v2 | ((uint32_t)v3 << 16);
        *(uint2*)(vt + off) = pk;
      }
    }
  }
}

// attn = laplacian(q@k^T/S + bias[i-j]) causal, TILED bf16 per batch.
// grid (32, 32, 4): jt, it, b; jt>it skipped (never read downstream).
__global__ __launch_bounds__(64) void k_gemm_sim(
    const uint16_t* __restrict__ qb, const uint16_t* __restrict__ kb,
    const float* __restrict__ bias_n, uint16_t* __restrict__ attn)
{
  int jt = blockIdx.x, it = blockIdx.y, bt = blockIdx.z;
  if (jt > it) return;
  __shared__ uint16_t lds[4 * 4096];
  f32x4 acc[4][4];
  wave_gemm_t(qb, 4, bt * 128 + it * 4, kb, 4, bt * 128 + jt * 4, 4, acc, lds);
  int lane = threadIdx.x & 63;
  int lane16 = lane & 15, quad = lane >> 4;
  uint16_t* ab = attn + (size_t)bt * S_ * S_;
  #pragma unroll
  for (int nt = 0; nt < 4; nt++) {
    int j = jt * 64 + nt * 16 + lane16;
    int joff = (j >> 5) * 512 + ((j >> 3) & 3) * 128 + (j & 7);
    #pragma unroll
    for (int mt = 0; mt < 4; mt++) {
      #pragma unroll
      for (int r = 0; r < 4; r++) {
        int i = it * 64 + mt * 16 + quad * 4 + r;
        float aval = 0.0f;
        if (j <= i) {
          float sim = acc[mt][nt][r] * (1.0f / 2048.0f) + bias_n[i - j];
          aval = laplacian_attn(sim);
        }
        ab[(size_t)(i >> 4) * 64 * 512 + joff + (i & 15) * 8] = f32_to_bf16(aval);
      }
    }
  }
}

// out = attn @ v, fp32 out. grid (16, 128): y = bt*32 + tt, it balanced.
__global__ __launch_bounds__(64) void k_gemm_out(
    const uint16_t* __restrict__ attn, const uint16_t* __restrict__ vT,
    float* __restrict__ out)
{
  __shared__ uint16_t lds[4 * 4096];
  int nx = blockIdx.x;
  int y = blockIdx.y;
  int bt = y >> 5, tt = y & 31;
  int it = (bt & 1) ? (31 - tt) : tt;
  int nkb = 2 * it + 2;                         // K = it*64+64, causal bound
  f32x4 acc[4][4];
  wave_gemm_t(attn + (size_t)bt * S_ * S_, 64, it * 4,
              vT + (size_t)bt * DV * S_, 64, nx * 4, nkb, acc, lds);
  int lane = threadIdx.x & 63;
  int lane16 = lane & 15, quad = lane >> 4;
  #pragma unroll
  for (int mt = 0; mt < 4; mt++)
    #pragma unroll
    for (int nt = 0; nt < 4; nt++)
      #pragma unroll
      for (int r = 0; r < 4; r++) {
        int i = it * 64 + mt * 16 + quad * 4 + r;
        int n = nx * 64 + nt * 16 + lane16;
        out[((size_t)bt * S_ + i) * DV + n] = acc[mt][nt][r];
      }
}

// ---------------------------------------------------------------------------

extern "C" void kernel_launch(void* const* d_in, const int* in_sizes, int n_in,
                              void* d_out, int out_size, void* d_ws, size_t ws_size,
                              hipStream_t stream)
{
  const float* x     = (const float*)d_in[0];
  const float* wqk   = (const float*)d_in[1];
  const float* bqk   = (const float*)d_in[2];
  const float* gamma = (const float*)d_in[3];
  const float* beta  = (const float*)d_in[4];
  const float* wv    = (const float*)d_in[5];
  const float* bv    = (const float*)d_in[6];
  const float* rel   = (const float*)d_in[7];
  float* out = (float*)d_out;

  char* ws = (char*)d_ws;
  size_t off = 0;
  uint16_t* xb     = (uint16_t*)(ws + off); off += (size_t)B_ * S_ * DIM_ * 2;  // 16 MB
  uint16_t* wT     = (uint16_t*)(ws + off); off += (size_t)NQV * DIM_ * 2;      // 2.25 MB
  uint16_t* qb     = (uint16_t*)(ws + off); off += (size_t)B_ * S_ * DQK * 2;   // 2 MB
  uint16_t* kb     = (uint16_t*)(ws + off); off += (size_t)B_ * S_ * DQK * 2;   // 2 MB
  uint16_t* vT     = (uint16_t*)(ws + off); off += (size_t)B_ * DV * S_ * 2;    // 16 MB
  uint16_t* attn   = (uint16_t*)(ws + off); off += (size_t)B_ * S_ * S_ * 2;    // 32 MB
  float*    bias_n = (float*)(ws + off);    off += (size_t)S_ * 4;              // 8 KB

  k_prep_x<<<dim3(B_ * S_ * DIM_ / 8 / 256), dim3(256), 0, stream>>>(x, xb);
  k_prep_w<<<dim3(NQV * DIM_ / 8 / 256), dim3(256), 0, stream>>>(wqk, wv, wT);
  k_bias<<<dim3(S_ / 256), dim3(256), 0, stream>>>(rel, bias_n);

  k_gemm_qkv<<<dim3(NQV / 64, B_ * S_ / 64), dim3(64), 0, stream>>>(
      xb, wT, bqk, gamma, beta, bv, qb, kb, vT);
  k_gemm_sim<<<dim3(S_ / 64, S_ / 64, B_), dim3(64), 0, stream>>>(
      qb, kb, bias_n, attn);
  k_gemm_out<<<dim3(DV / 64, B_ * S_ / 64), dim3(64), 0, stream>>>(
      attn, vT, out);
}

// Round 9
// 226.268 us; speedup vs baseline: 1.6638x; 1.1871x over previous
//
#include <hip/hip_runtime.h>
#include <stdint.h>

// ---------------------------------------------------------------------------
// SingleHeadedAttention (Mega-style, laplacian attn fn, causal, T5 rel bias)
// B=4, S=2048, DIM=1024, DQK=128, DV=1024.  fp32 in/out, bf16 MFMA internals.
// R8: R7 with the k_gemm_out grid bug fixed (grid.y 32 -> 64; bt=y>>4 needs
//     y in 0..63 for 4 batches — batches 2,3 were never computed in R7).
//   TILED: element (row,k) of [R][K] at
//     ((row>>4)*(K>>5) + (k>>5))*512 + ((k>>3)&3)*128 + (row&15)*8 + (k&7).
//   Lane l's MFMA fragment of a 16x32 block = 16 contiguous bytes at
//   base + l*16 -> one coalesced global_load_dwordx4 per fragment. No LDS,
//   no barriers, no DMA in the GEMMs; register double-buffer (2 k-blocks);
//   4 independent 64x64 waves per 256-thread block (128x128 block tile).
// ---------------------------------------------------------------------------

#define B_   4
#define S_   2048
#define DIM_ 1024
#define DQK  128
#define DV   1024
#define NQV  1152

typedef __attribute__((ext_vector_type(8))) short short8;   // 8 bf16
typedef __attribute__((ext_vector_type(4))) float f32x4;    // MFMA C/D

__device__ __forceinline__ uint16_t f32_to_bf16(float f) {
  uint32_t u = __float_as_uint(f);
  u += 0x7FFFu + ((u >> 16) & 1u);          // round-to-nearest-even
  return (uint16_t)(u >> 16);
}

__device__ __forceinline__ float silu_f(float x) {
  return x / (1.0f + expf(-x));
}

__device__ __forceinline__ float laplacian_attn(float x) {
  return 0.5f * (1.0f + erff((x - 0.70710678118654752f) * 0.79788456080286536f));
}

// ---- wave-private 64x64 GEMM on TILED operands, register pipeline ---------
// A tiled [RA][K] row-blocks rbA..+3, Bt tiled [RB][K] row-blocks rbB..+3.
// KBa/KBb = K>>5. nkb even, >=2. Fragments global->VGPR, contiguous 16B/lane.
__device__ __forceinline__ void wave_gemm_r(
    const uint16_t* __restrict__ A, int KBa, int rbA,
    const uint16_t* __restrict__ Bt, int KBb, int rbB,
    int nkb, f32x4 acc[4][4])
{
  const int lane = threadIdx.x & 63;

  const uint16_t* pa[4];
  const uint16_t* pb[4];
  #pragma unroll
  for (int mt = 0; mt < 4; mt++)
    pa[mt] = A + (size_t)(rbA + mt) * KBa * 512 + lane * 8;
  #pragma unroll
  for (int nt = 0; nt < 4; nt++)
    pb[nt] = Bt + (size_t)(rbB + nt) * KBb * 512 + lane * 8;

  #pragma unroll
  for (int mt = 0; mt < 4; mt++)
    #pragma unroll
    for (int nt = 0; nt < 4; nt++) {
      f32x4 z = {0.0f, 0.0f, 0.0f, 0.0f};
      acc[mt][nt] = z;
    }

  short8 fa0[4], fb0[4], fa1[4], fb1[4];

  auto loads = [&](short8 fa[4], short8 fb[4], int kb) {
    #pragma unroll
    for (int mt = 0; mt < 4; mt++)
      fa[mt] = *(const short8*)(pa[mt] + (size_t)kb * 512);
    #pragma unroll
    for (int nt = 0; nt < 4; nt++)
      fb[nt] = *(const short8*)(pb[nt] + (size_t)kb * 512);
  };
  auto mfmas = [&](short8 fa[4], short8 fb[4]) {
    #pragma unroll
    for (int mt = 0; mt < 4; mt++)
      #pragma unroll
      for (int nt = 0; nt < 4; nt++)
        acc[mt][nt] = __builtin_amdgcn_mfma_f32_16x16x32_bf16(
            fa[mt], fb[nt], acc[mt][nt], 0, 0, 0);
  };

  loads(fa0, fb0, 0);
  loads(fa1, fb1, 1);
  for (int kb = 2; kb < nkb; kb += 2) {
    mfmas(fa0, fb0);
    loads(fa0, fb0, kb);
    mfmas(fa1, fb1);
    loads(fa1, fb1, kb + 1);
  }
  mfmas(fa0, fb0);
  mfmas(fa1, fb1);
}

// 256-thread block = 4 independent waves over a 128x128 tile.
// wave w: rows +(w>>1)*64 (row-blocks +(w>>1)*4), cols +(w&1)*64.
#define WAVE_PREAMBLE                                  \
  int lane = threadIdx.x & 63;                         \
  int wave = threadIdx.x >> 6;                         \
  int lane16 = lane & 15;                              \
  int quad = lane >> 4;                                \
  int wrow = (wave >> 1) * 64;                         \
  int wcol = (wave & 1) * 64;

// ---- prep kernels ----------------------------------------------------------

// x fp32 [8192][1024] -> xb TILED bf16 (output linear/coalesced).
__global__ __launch_bounds__(256) void k_prep_x(
    const float* __restrict__ x, uint16_t* __restrict__ xb)
{
  int t = blockIdx.x * 256 + threadIdx.x;      // 0 .. 8192*128-1
  int i16 = t & 15, oct = (t >> 4) & 3, kb = (t >> 6) & 31, ib = t >> 11;
  const float* src = x + (size_t)(ib * 16 + i16) * DIM_ + kb * 32 + oct * 8;
  float4 a = *(const float4*)src;
  float4 b = *(const float4*)(src + 4);
  short8 o;
  o[0] = f32_to_bf16(a.x); o[1] = f32_to_bf16(a.y);
  o[2] = f32_to_bf16(a.z); o[3] = f32_to_bf16(a.w);
  o[4] = f32_to_bf16(b.x); o[5] = f32_to_bf16(b.y);
  o[6] = f32_to_bf16(b.z); o[7] = f32_to_bf16(b.w);
  *(short8*)(xb + (size_t)t * 8) = o;
}

// wqk [1024][128], wv [1024][1024] fp32 -> wT TILED bf16, rows n=0..1151
__global__ __launch_bounds__(256) void k_prep_w(
    const float* __restrict__ wqk, const float* __restrict__ wv,
    uint16_t* __restrict__ wT)
{
  int t = blockIdx.x * 256 + threadIdx.x;      // 0 .. 1152*128-1
  int n16 = t & 15, oct = (t >> 4) & 3, kb = (t >> 6) & 31, nb = t >> 11;
  int n = nb * 16 + n16;
  int k0 = kb * 32 + oct * 8;
  short8 o;
  if (n < DQK) {
    #pragma unroll
    for (int j = 0; j < 8; j++)
      o[j] = f32_to_bf16(wqk[(size_t)(k0 + j) * DQK + n]);
  } else {
    int nn = n - DQK;
    #pragma unroll
    for (int j = 0; j < 8; j++)
      o[j] = f32_to_bf16(wv[(size_t)(k0 + j) * DV + nn]);
  }
  *(short8*)(wT + (size_t)t * 8) = o;
}

// bias_n[n] = rel_bias[bucket(n)] * sqrt(DQK)
__global__ __launch_bounds__(256) void k_bias(
    const float* __restrict__ rel, float* __restrict__ bias_n)
{
  int n = blockIdx.x * blockDim.x + threadIdx.x;
  if (n >= S_) return;
  int bucket;
  if (n < 16) {
    bucket = n;
  } else {
    float tt = logf((float)n * 0.0625f) / 2.0794415416798357f * 16.0f;
    int vl = 16 + (int)tt;
    bucket = vl < 31 ? vl : 31;
  }
  bias_n[n] = rel[bucket] * 11.313708498984761f;
}

// ---- GEMM kernels ----------------------------------------------------------

// fused projections. grid (9, 64). bx==0 -> q/k epilogue; bx>=1 -> v -> vT.
__global__ __launch_bounds__(256, 3) void k_gemm_qkv(
    const uint16_t* __restrict__ xb, const uint16_t* __restrict__ wT,
    const float* __restrict__ bqk, const float* __restrict__ gamma,
    const float* __restrict__ beta, const float* __restrict__ bv,
    uint16_t* __restrict__ qb, uint16_t* __restrict__ kb,
    uint16_t* __restrict__ vT)
{
  int bx = blockIdx.x, by = blockIdx.y;
  WAVE_PREAMBLE
  f32x4 acc[4][4];
  wave_gemm_r(xb, DIM_ >> 5, by * 8 + (wave >> 1) * 4,
              wT, DIM_ >> 5, bx * 8 + (wave & 1) * 4,
              DIM_ >> 5, acc);

  if (bx == 0) {
    #pragma unroll
    for (int nt = 0; nt < 4; nt++) {
      int col = wcol + nt * 16 + lane16;           // 0..127
      float bb = bqk[col];
      float g0 = gamma[col], b0 = beta[col];
      float g1 = gamma[DQK + col], b1 = beta[DQK + col];
      int coff = (col >> 5) * 512 + ((col >> 3) & 3) * 128 + (col & 7);
      #pragma unroll
      for (int mt = 0; mt < 4; mt++) {
        int rb = by * 8 + (wave >> 1) * 4 + mt;    // row-block, KB=4
        size_t base = (size_t)rb * 4 * 512 + coff + (size_t)(quad * 4) * 8;
        #pragma unroll
        for (int r = 0; r < 4; r++) {
          float s = silu_f(acc[mt][nt][r] + bb);
          qb[base + r * 8] = f32_to_bf16(s * g0 + b0);
          kb[base + r * 8] = f32_to_bf16(s * g1 + b1);
        }
      }
    }
  } else {
    int b = by >> 4;                               // batch (by*128 / 2048)
    uint16_t* vt = vT + (size_t)b * DV * S_;
    #pragma unroll
    for (int nt = 0; nt < 4; nt++) {
      int n = (bx - 1) * 128 + wcol + nt * 16 + lane16;   // 0..1023
      float bb = bv[n];
      #pragma unroll
      for (int mt = 0; mt < 4; mt++) {
        int j0l = (by & 15) * 128 + wrow + mt * 16 + quad * 4; // local seq
        uint16_t v0 = f32_to_bf16(silu_f(acc[mt][nt][0] + bb));
        uint16_t v1 = f32_to_bf16(silu_f(acc[mt][nt][1] + bb));
        uint16_t v2 = f32_to_bf16(silu_f(acc[mt][nt][2] + bb));
        uint16_t v3 = f32_to_bf16(silu_f(acc[mt][nt][3] + bb));
        size_t off = (size_t)((n >> 4) * 64 + (j0l >> 5)) * 512 +
                     ((j0l >> 3) & 3) * 128 + (n & 15) * 8 + (j0l & 7);
        uint2 pk;
        pk.x = (uint32_t)v0 | ((uint32_t)v1 << 16);
        pk.y = (uint32_t)v2 | ((uint32_t)v3 << 16);
        *(uint2*)(vt + off) = pk;
      }
    }
  }
}

// attn = laplacian(q@k^T/S + bias[i-j]) causal, TILED bf16 per batch.
// grid (16, 16, 4): jt, it, b; jt>it skipped (tiles never read downstream).
__global__ __launch_bounds__(256, 3) void k_gemm_sim(
    const uint16_t* __restrict__ qb, const uint16_t* __restrict__ kb,
    const float* __restrict__ bias_n, uint16_t* __restrict__ attn)
{
  int jt = blockIdx.x, it = blockIdx.y, bt = blockIdx.z;
  if (jt > it) return;
  WAVE_PREAMBLE
  f32x4 acc[4][4];
  wave_gemm_r(qb, 4, bt * 128 + it * 8 + (wave >> 1) * 4,
              kb, 4, bt * 128 + jt * 8 + (wave & 1) * 4,
              4, acc);
  uint16_t* ab = attn + (size_t)bt * S_ * S_;
  #pragma unroll
  for (int nt = 0; nt < 4; nt++) {
    int j = jt * 128 + wcol + nt * 16 + lane16;
    size_t joff = (size_t)(j >> 5) * 512 + ((j >> 3) & 3) * 128 + (j & 7);
    #pragma unroll
    for (int mt = 0; mt < 4; mt++) {
      #pragma unroll
      for (int r = 0; r < 4; r++) {
        int i = it * 128 + wrow + mt * 16 + quad * 4 + r;
        float aval = 0.0f;
        if (j <= i) {
          float sim = acc[mt][nt][r] * (1.0f / 2048.0f) + bias_n[i - j];
          aval = laplacian_attn(sim);
        }
        ab[(size_t)(i >> 4) * 64 * 512 + joff + (size_t)(i & 15) * 8] =
            f32_to_bf16(aval);
      }
    }
  }
}

// out = attn @ v, fp32 out. grid (8, 64): y = bt*16 + tt, it balanced so
// co-resident groups get ~constant K; nkb = 4*it+4 (causal bound).
__global__ __launch_bounds__(256, 3) void k_gemm_out(
    const uint16_t* __restrict__ attn, const uint16_t* __restrict__ vT,
    float* __restrict__ out)
{
  int nx = blockIdx.x;
  int y = blockIdx.y;
  int bt = y >> 4, tt = y & 15;
  int it = (bt & 1) ? (15 - tt) : tt;
  int nkb = 4 * it + 4;
  WAVE_PREAMBLE
  f32x4 acc[4][4];
  wave_gemm_r(attn + (size_t)bt * S_ * S_, 64, it * 8 + (wave >> 1) * 4,
              vT + (size_t)bt * DV * S_, 64, nx * 8 + (wave & 1) * 4,
              nkb, acc);
  #pragma unroll
  for (int mt = 0; mt < 4; mt++)
    #pragma unroll
    for (int nt = 0; nt < 4; nt++)
      #pragma unroll
      for (int r = 0; r < 4; r++) {
        int i = it * 128 + wrow + mt * 16 + quad * 4 + r;
        int n = nx * 128 + wcol + nt * 16 + lane16;
        out[((size_t)bt * S_ + i) * DV + n] = acc[mt][nt][r];
      }
}

// ---------------------------------------------------------------------------

extern "C" void kernel_launch(void* const* d_in, const int* in_sizes, int n_in,
                              void* d_out, int out_size, void* d_ws, size_t ws_size,
                              hipStream_t stream)
{
  const float* x     = (const float*)d_in[0];
  const float* wqk   = (const float*)d_in[1];
  const float* bqk   = (const float*)d_in[2];
  const float* gamma = (const float*)d_in[3];
  const float* beta  = (const float*)d_in[4];
  const float* wv    = (const float*)d_in[5];
  const float* bv    = (const float*)d_in[6];
  const float* rel   = (const float*)d_in[7];
  float* out = (float*)d_out;

  char* ws = (char*)d_ws;
  size_t off = 0;
  uint16_t* xb     = (uint16_t*)(ws + off); off += (size_t)B_ * S_ * DIM_ * 2;  // 16 MB
  uint16_t* wT     = (uint16_t*)(ws + off); off += (size_t)NQV * DIM_ * 2;      // 2.25 MB
  uint16_t* qb     = (uint16_t*)(ws + off); off += (size_t)B_ * S_ * DQK * 2;   // 2 MB
  uint16_t* kb     = (uint16_t*)(ws + off); off += (size_t)B_ * S_ * DQK * 2;   // 2 MB
  uint16_t* vT     = (uint16_t*)(ws + off); off += (size_t)B_ * DV * S_ * 2;    // 16 MB
  uint16_t* attn   = (uint16_t*)(ws + off); off += (size_t)B_ * S_ * S_ * 2;    // 32 MB
  float*    bias_n = (float*)(ws + off);    off += (size_t)S_ * 4;              // 8 KB

  k_prep_x<<<dim3(B_ * S_ * DIM_ / 8 / 256), dim3(256), 0, stream>>>(x, xb);
  k_prep_w<<<dim3(NQV * DIM_ / 8 / 256), dim3(256), 0, stream>>>(wqk, wv, wT);
  k_bias<<<dim3(S_ / 256), dim3(256), 0, stream>>>(rel, bias_n);

  k_gemm_qkv<<<dim3(NQV / 128, B_ * S_ / 128), dim3(256), 0, stream>>>(
      xb, wT, bqk, gamma, beta, bv, qb, kb, vT);
  k_gemm_sim<<<dim3(S_ / 128, S_ / 128, B_), dim3(256), 0, stream>>>(
      qb, kb, bias_n, attn);
  k_gemm_out<<<dim3(DV / 128, B_ * S_ / 128), dim3(256), 0, stream>>>(
      attn, vT, out);
}